// Round 6
// baseline (406.550 us; speedup 1.0000x reference)
//
#include <hip/hip_runtime.h>
#include <hip/hip_bf16.h>
#include <math.h>

#define DIMC 512
#define NPT  4096
#define BATCH 16
#define KSPLIT 8

typedef __bf16 bf16x4 __attribute__((ext_vector_type(4)));
typedef __bf16 bf16x8 __attribute__((ext_vector_type(8)));
typedef float  f32x4  __attribute__((ext_vector_type(4)));

typedef const __attribute__((address_space(1))) unsigned int guint;
typedef __attribute__((address_space(3))) unsigned int luint;

__device__ inline void gl_lds16(const void* g, void* l) {
  __builtin_amdgcn_global_load_lds((guint*)g, (luint*)l, 16, 0, 0);
}

// BK=64 staging/read swizzle (rule #21: linear LDS dest for gl_lds, inverse-
// swizzled GLOBAL source, swizzled chunk index on ds_read):
//   lane l stages 16B of row (chunk*8 + l>>3), LDS slot (l&7);
//   source k-chunk = (l&7) ^ (l>>3 & 7)  -> read chunk' = c ^ (row&7).

// ---------------------------------------------------------------------------
// Gram, upper-triangle 128-tiles only, split-K x8, XCD-swizzled 1D grid.
// Grid 1280 = 8 XCD * 16 pair-groups * 10 tiles; 4 blocks/CU resident.
// ---------------------------------------------------------------------------
__global__ __launch_bounds__(256, 4) void gram_split(
    const __bf16* __restrict__ xb, float* __restrict__ Gp)
{
  static const int TI[10] = {0,0,0,0,1,1,1,2,2,3};
  static const int TJ[10] = {0,1,2,3,1,2,3,2,3,3};
  const int id = blockIdx.x;
  const int xcd = id & 7, slot = id >> 3;
  const int g = slot / 10, t = slot % 10;
  const int pair = xcd + 8 * g;          // 0..127
  const int b = pair >> 3, s = pair & 7;
  const int m0 = TI[t] * 128, n0 = TJ[t] * 128;

  const __bf16* A = xb + (long)b * DIMC * NPT;
  float* C = Gp + (long)pair * DIMC * DIMC;

  __shared__ alignas(16) __bf16 As[128 * 64];
  __shared__ alignas(16) __bf16 Bs[128 * 64];

  const int tid  = threadIdx.x;
  const int wave = tid >> 6, lane = tid & 63;
  const int wr = wave >> 1, wc = wave & 1;
  const int q = lane >> 4, p = lane & 15;
  const int r8 = lane >> 3;
  const int sk8 = (((lane & 7) ^ (r8 & 7)) * 8);   // swizzled source k-offset
  const int px = p & 7;

  f32x4 acc[4][4];
#pragma unroll
  for (int i = 0; i < 4; ++i)
#pragma unroll
    for (int j = 0; j < 4; ++j) acc[i][j] = (f32x4){0.f, 0.f, 0.f, 0.f};

  const __bf16* gA = A + (long)m0 * NPT;
  const __bf16* gB = A + (long)n0 * NPT;
  const int kbeg = s * (NPT / KSPLIT), kend = kbeg + NPT / KSPLIT;

  for (int k0 = kbeg; k0 < kend; k0 += 64) {
    __syncthreads();
#pragma unroll
    for (int h = 0; h < 4; ++h) {
      const int chunk = wave + h * 4;                 // 0..15, rows chunk*8..+8
      gl_lds16(gA + (long)(chunk * 8 + r8) * NPT + k0 + sk8, &As[chunk * 512]);
      gl_lds16(gB + (long)(chunk * 8 + r8) * NPT + k0 + sk8, &Bs[chunk * 512]);
    }
    __syncthreads();

#pragma unroll
    for (int kk = 0; kk < 2; ++kk) {
      bf16x8 af[4], bfv[4];
#pragma unroll
      for (int i = 0; i < 4; ++i)
        af[i] = ((const bf16x8*)As)[(wr * 64 + i * 16 + p) * 8 + ((kk * 4 + q) ^ px)];
#pragma unroll
      for (int j = 0; j < 4; ++j)
        bfv[j] = ((const bf16x8*)Bs)[(wc * 64 + j * 16 + p) * 8 + ((kk * 4 + q) ^ px)];
#pragma unroll
      for (int i = 0; i < 4; ++i)
#pragma unroll
        for (int j = 0; j < 4; ++j)
          acc[i][j] = __builtin_amdgcn_mfma_f32_16x16x32_bf16(af[i], bfv[j], acc[i][j], 0, 0, 0);
    }
  }

#pragma unroll
  for (int i = 0; i < 4; ++i) {
    const int row = m0 + wr * 64 + i * 16 + q * 4;
#pragma unroll
    for (int j = 0; j < 4; ++j) {
      const int col = n0 + wc * 64 + j * 16 + p;
#pragma unroll
      for (int r = 0; r < 4; ++r)
        C[(long)(row + r) * DIMC + col] = acc[i][j][r];
    }
  }
}

// ---------------------------------------------------------------------------
// Reduce split-K partials of upper 64-tiles, emit Gh/Gl hi/lo, mirror lower.
// ---------------------------------------------------------------------------
__global__ __launch_bounds__(256) void gram_reduce_mirror(
    const float* __restrict__ Gp, __bf16* __restrict__ Gh, __bf16* __restrict__ Gl)
{
  const int bid = blockIdx.x;
  const int b = bid / 36;
  int rem = bid % 36, I = 0;
  while (rem >= 8 - I) { rem -= 8 - I; ++I; }
  const int J = I + rem;

  __shared__ float T[64][65];
  const int tid = threadIdx.x;
  const int r = tid >> 2, c0 = (tid & 3) * 16;

  float v[16];
#pragma unroll
  for (int e = 0; e < 16; ++e) v[e] = 0.f;
#pragma unroll
  for (int s = 0; s < KSPLIT; ++s) {
    const float* src = Gp + (long)(b * KSPLIT + s) * DIMC * DIMC
                          + (long)(I * 64 + r) * DIMC + J * 64 + c0;
#pragma unroll
    for (int q = 0; q < 4; ++q) {
      float4 t4 = ((const float4*)src)[q];
      v[q * 4 + 0] += t4.x; v[q * 4 + 1] += t4.y;
      v[q * 4 + 2] += t4.z; v[q * 4 + 3] += t4.w;
    }
  }

  const long gbase = (long)b * DIMC * DIMC;
#pragma unroll
  for (int q = 0; q < 4; ++q) {
    bf16x4 h, l;
#pragma unroll
    for (int e = 0; e < 4; ++e) {
      float f = v[q * 4 + e];
      __bf16 hh = (__bf16)f;
      h[e] = hh; l[e] = (__bf16)(f - (float)hh);
    }
    const long o = gbase + (long)(I * 64 + r) * DIMC + J * 64 + c0 + q * 4;
    *(bf16x4*)(Gh + o) = h;
    *(bf16x4*)(Gl + o) = l;
  }
#pragma unroll
  for (int e = 0; e < 16; ++e) T[r][c0 + e] = v[e];
  __syncthreads();
  if (I != J) {
#pragma unroll
    for (int q = 0; q < 4; ++q) {
      bf16x4 h, l;
#pragma unroll
      for (int e = 0; e < 4; ++e) {
        float f = T[c0 + q * 4 + e][r];
        __bf16 hh = (__bf16)f;
        h[e] = hh; l[e] = (__bf16)(f - (float)hh);
      }
      const long o = gbase + (long)(J * 64 + r) * DIMC + I * 64 + c0 + q * 4;
      *(bf16x4*)(Gh + o) = h;
      *(bf16x4*)(Gl + o) = l;
    }
  }
}

// ---------------------------------------------------------------------------
// 3-term hi/lo NT GEMM, 64M x 64N tile, BK=64. 4 waves (2x2, each 32x32).
// 8 gl_lds + 24 MFMA per iter. Grid (8, 8, BATCH) = 1024 blocks, 4/CU.
// ---------------------------------------------------------------------------
template <bool SPLIT_OUT>
__global__ __launch_bounds__(256, 4) void gemm3_nt(
    const __bf16* __restrict__ Ah, const __bf16* __restrict__ Al,
    const __bf16* __restrict__ Bh, const __bf16* __restrict__ Bl,
    float* __restrict__ Cf, __bf16* __restrict__ Ch, __bf16* __restrict__ Cl,
    int K, long sA, long sB, long sC, float alpha)
{
  const int b = blockIdx.z;
  Ah += (long)b * sA;  Al += (long)b * sA;
  Bh += (long)b * sB;  Bl += (long)b * sB;
  const int m0 = blockIdx.y * 64, n0 = blockIdx.x * 64;

  __shared__ alignas(16) __bf16 sAh[64 * 64], sAl[64 * 64];
  __shared__ alignas(16) __bf16 sBh[64 * 64], sBl[64 * 64];

  const int tid  = threadIdx.x;
  const int wave = tid >> 6, lane = tid & 63;
  const int wr = wave >> 1, wc = wave & 1;
  const int q = lane >> 4, p = lane & 15;
  const int r8 = lane >> 3;
  const int sk8 = (((lane & 7) ^ (r8 & 7)) * 8);
  const int px = p & 7;

  f32x4 acc[2][2];
#pragma unroll
  for (int i = 0; i < 2; ++i)
#pragma unroll
    for (int j = 0; j < 2; ++j) acc[i][j] = (f32x4){0.f, 0.f, 0.f, 0.f};

  for (int k0 = 0; k0 < K; k0 += 64) {
    __syncthreads();
#pragma unroll
    for (int h = 0; h < 2; ++h) {
      const int chunk = wave + h * 4;                 // 0..7, rows chunk*8..+8
      const long arow = (long)(m0 + chunk * 8 + r8) * K + k0 + sk8;
      const long brow = (long)(n0 + chunk * 8 + r8) * K + k0 + sk8;
      gl_lds16(Ah + arow, &sAh[chunk * 512]);
      gl_lds16(Al + arow, &sAl[chunk * 512]);
      gl_lds16(Bh + brow, &sBh[chunk * 512]);
      gl_lds16(Bl + brow, &sBl[chunk * 512]);
    }
    __syncthreads();

#pragma unroll
    for (int kk = 0; kk < 2; ++kk) {
      bf16x8 fah[2], fal[2], fbh[2], fbl[2];
#pragma unroll
      for (int i = 0; i < 2; ++i) {
        const int idx = (wr * 32 + i * 16 + p) * 8 + ((kk * 4 + q) ^ px);
        fah[i] = ((const bf16x8*)sAh)[idx];
        fal[i] = ((const bf16x8*)sAl)[idx];
      }
#pragma unroll
      for (int j = 0; j < 2; ++j) {
        const int idx = (wc * 32 + j * 16 + p) * 8 + ((kk * 4 + q) ^ px);
        fbh[j] = ((const bf16x8*)sBh)[idx];
        fbl[j] = ((const bf16x8*)sBl)[idx];
      }
#pragma unroll
      for (int i = 0; i < 2; ++i)
#pragma unroll
        for (int j = 0; j < 2; ++j) {
          acc[i][j] = __builtin_amdgcn_mfma_f32_16x16x32_bf16(fah[i], fbh[j], acc[i][j], 0, 0, 0);
          acc[i][j] = __builtin_amdgcn_mfma_f32_16x16x32_bf16(fah[i], fbl[j], acc[i][j], 0, 0, 0);
          acc[i][j] = __builtin_amdgcn_mfma_f32_16x16x32_bf16(fal[i], fbh[j], acc[i][j], 0, 0, 0);
        }
    }
  }

#pragma unroll
  for (int i = 0; i < 2; ++i) {
    const int row = m0 + wr * 32 + i * 16 + q * 4;
#pragma unroll
    for (int j = 0; j < 2; ++j) {
      const int col = n0 + wc * 32 + j * 16 + p;
#pragma unroll
      for (int r = 0; r < 4; ++r) {
        const float f = acc[i][j][r] * alpha;
        const long o = (long)b * sC + (long)(row + r) * DIMC + col;
        if (SPLIT_OUT) {
          __bf16 hh = (__bf16)f;
          Ch[o] = hh;
          Cl[o] = (__bf16)(f - (float)hh);
        } else {
          Cf[o] = f;
        }
      }
    }
  }
}

// ---------------------------------------------------------------------------
// Single-term NT GEMM bf16, 64M x 128N tile (M = P . Wv^T). BK=64: 8 iters.
// ---------------------------------------------------------------------------
__global__ __launch_bounds__(256, 2) void gemm_nt64x128(
    const __bf16* __restrict__ A, const __bf16* __restrict__ B,
    __bf16* __restrict__ C, int K, long sA, long sB, long sC)
{
  const int b = blockIdx.z;
  A += (long)b * sA;  B += (long)b * sB;  C += (long)b * sC;
  const int m0 = blockIdx.y * 64, n0 = blockIdx.x * 128;

  __shared__ alignas(16) __bf16 As[64 * 64];
  __shared__ alignas(16) __bf16 Bs[128 * 64];

  const int tid  = threadIdx.x;
  const int wave = tid >> 6, lane = tid & 63;
  const int wr = wave >> 1, wc = wave & 1;
  const int q = lane >> 4, p = lane & 15;
  const int r8 = lane >> 3;
  const int sk8 = (((lane & 7) ^ (r8 & 7)) * 8);
  const int px = p & 7;

  f32x4 acc[2][4];
#pragma unroll
  for (int i = 0; i < 2; ++i)
#pragma unroll
    for (int j = 0; j < 4; ++j) acc[i][j] = (f32x4){0.f, 0.f, 0.f, 0.f};

  for (int k0 = 0; k0 < K; k0 += 64) {
    __syncthreads();
#pragma unroll
    for (int h = 0; h < 2; ++h) {
      const int chunk = wave + h * 4;
      gl_lds16(A + (long)(m0 + chunk * 8 + r8) * K + k0 + sk8, &As[chunk * 512]);
    }
#pragma unroll
    for (int h = 0; h < 4; ++h) {
      const int chunk = wave + h * 4;
      gl_lds16(B + (long)(n0 + chunk * 8 + r8) * K + k0 + sk8, &Bs[chunk * 512]);
    }
    __syncthreads();

#pragma unroll
    for (int kk = 0; kk < 2; ++kk) {
      bf16x8 af[2], bfv[4];
#pragma unroll
      for (int i = 0; i < 2; ++i)
        af[i] = ((const bf16x8*)As)[(wr * 32 + i * 16 + p) * 8 + ((kk * 4 + q) ^ px)];
#pragma unroll
      for (int j = 0; j < 4; ++j)
        bfv[j] = ((const bf16x8*)Bs)[(wc * 64 + j * 16 + p) * 8 + ((kk * 4 + q) ^ px)];
#pragma unroll
      for (int i = 0; i < 2; ++i)
#pragma unroll
        for (int j = 0; j < 4; ++j)
          acc[i][j] = __builtin_amdgcn_mfma_f32_16x16x32_bf16(af[i], bfv[j], acc[i][j], 0, 0, 0);
    }
  }

#pragma unroll
  for (int i = 0; i < 2; ++i) {
    const int row = m0 + wr * 32 + i * 16 + q * 4;
#pragma unroll
    for (int j = 0; j < 4; ++j) {
      const int col = n0 + wc * 64 + j * 16 + p;
#pragma unroll
      for (int r = 0; r < 4; ++r)
        C[(long)(row + r) * DIMC + col] = (__bf16)acc[i][j][r];
    }
  }
}

// ---------------------------------------------------------------------------
// Final GEMM (NN, direct from xb): out_b[d,n] = sum_c Mm_b[d,c] xb_b[c,n].
// BK=64 single-buffer, reg-packed transposed B (stride-34 dword rows).
// ---------------------------------------------------------------------------
__global__ __launch_bounds__(256, 3) void gemm_final(
    const __bf16* __restrict__ Mm, const __bf16* __restrict__ xb,
    float* __restrict__ out)
{
  const int id = blockIdx.x;
  const int xcd = id & 7, slot = id >> 3;
  const int g = slot >> 7, tile = slot & 127;
  const int b = xcd + 8 * g;
  const int m0 = (tile >> 5) * 128, n0 = (tile & 31) * 128;

  const __bf16* A = Mm + (long)b * DIMC * DIMC;
  const __bf16* B = xb + (long)b * DIMC * NPT;
  float* C = out + (long)b * DIMC * NPT;
  const int K = DIMC;

  __shared__ alignas(16) __bf16 As[128 * 64];
  __shared__ alignas(16) unsigned int Bs[128 * 34];   // [n][c-dword], stride 34

  const int tid  = threadIdx.x;
  const int wave = tid >> 6, lane = tid & 63;
  const int wr = wave >> 1, wc = wave & 1;
  const int q = lane >> 4, p = lane & 15;
  const int r8 = lane >> 3;
  const int sk8 = (((lane & 7) ^ (r8 & 7)) * 8);
  const int px = p & 7;

  const int ng = tid & 31;    // n quad: n_local = ng*4 .. +3
  const int cg = tid >> 5;    // c octet: c_local = cg*8 .. +7

  f32x4 acc[4][4];
#pragma unroll
  for (int i = 0; i < 4; ++i)
#pragma unroll
    for (int j = 0; j < 4; ++j) acc[i][j] = (f32x4){0.f, 0.f, 0.f, 0.f};

  const __bf16* gA = A + (long)m0 * K;
  const __bf16* gBrow = B + n0 + ng * 4;

  for (int k0 = 0; k0 < K; k0 += 64) {
    __syncthreads();
#pragma unroll
    for (int h = 0; h < 4; ++h) {
      const int chunk = wave + h * 4;                 // 0..15
      gl_lds16(gA + (long)(chunk * 8 + r8) * K + k0 + sk8, &As[chunk * 512]);
    }
    // B tile: 64 c-rows x 128 n. 8 c-rows x 4 n per thread, coalesced loads.
    uint2 rd[8];
#pragma unroll
    for (int r = 0; r < 8; ++r)
      rd[r] = *(const uint2*)(gBrow + (long)(k0 + cg * 8 + r) * NPT);
#pragma unroll
    for (int nn = 0; nn < 4; ++nn) {
      unsigned int s[8];
#pragma unroll
      for (int r = 0; r < 8; ++r) s[r] = (nn < 2) ? rd[r].x : rd[r].y;
      unsigned int dw[4];
#pragma unroll
      for (int t = 0; t < 4; ++t) {
        if (nn & 1)
          dw[t] = (s[2 * t] >> 16) | (s[2 * t + 1] & 0xffff0000u);
        else
          dw[t] = (s[2 * t] & 0xffffu) | (s[2 * t + 1] << 16);
      }
      unsigned int* bp = &Bs[(ng * 4 + nn) * 34 + cg * 4];
      uint2 o0; o0.x = dw[0]; o0.y = dw[1];
      uint2 o1; o1.x = dw[2]; o1.y = dw[3];
      *(uint2*)bp = o0;            // ds_write_b64, 8B aligned
      *(uint2*)(bp + 2) = o1;
    }
    __syncthreads();

#pragma unroll
    for (int kk = 0; kk < 2; ++kk) {
      bf16x8 af[4], bfv[4];
#pragma unroll
      for (int i = 0; i < 4; ++i)
        af[i] = ((const bf16x8*)As)[(wr * 64 + i * 16 + p) * 8 + ((kk * 4 + q) ^ px)];
#pragma unroll
      for (int j = 0; j < 4; ++j) {
        const unsigned int* bp = &Bs[(wc * 64 + j * 16 + p) * 34 + kk * 16 + q * 4];
        const uint2 lo = *(const uint2*)bp;
        const uint2 hi = *(const uint2*)(bp + 2);
        union { uint4 u; bf16x8 v; } cvt;
        cvt.u.x = lo.x; cvt.u.y = lo.y; cvt.u.z = hi.x; cvt.u.w = hi.y;
        bfv[j] = cvt.v;
      }
#pragma unroll
      for (int i = 0; i < 4; ++i)
#pragma unroll
        for (int j = 0; j < 4; ++j)
          acc[i][j] = __builtin_amdgcn_mfma_f32_16x16x32_bf16(af[i], bfv[j], acc[i][j], 0, 0, 0);
    }
  }

#pragma unroll
  for (int i = 0; i < 4; ++i) {
    const int row = m0 + wr * 64 + i * 16 + q * 4;
#pragma unroll
    for (int j = 0; j < 4; ++j) {
      const int col = n0 + wc * 64 + j * 16 + p;
#pragma unroll
      for (int r = 0; r < 4; ++r)
        C[(long)(row + r) * NPT + col] = acc[i][j][r];
    }
  }
}

// ---------------------------------------------------------------------------
// Row softmax over 512 cols, fp32 in -> bf16 out. One wave per row.
// ---------------------------------------------------------------------------
__global__ __launch_bounds__(256) void softmax_rows(
    const float* __restrict__ S, __bf16* __restrict__ P)
{
  const int row = blockIdx.x * 4 + (threadIdx.x >> 6);
  const int lane = threadIdx.x & 63;
  const float4* s4 = (const float4*)(S + (long)row * DIMC);
  float4 a = s4[lane * 2], b = s4[lane * 2 + 1];
  float v[8] = {a.x, a.y, a.z, a.w, b.x, b.y, b.z, b.w};
  float m = v[0];
#pragma unroll
  for (int i = 1; i < 8; ++i) m = fmaxf(m, v[i]);
#pragma unroll
  for (int off = 32; off > 0; off >>= 1) m = fmaxf(m, __shfl_xor(m, off));
  float e[8], sum = 0.f;
#pragma unroll
  for (int i = 0; i < 8; ++i) { e[i] = expf(v[i] - m); sum += e[i]; }
#pragma unroll
  for (int off = 32; off > 0; off >>= 1) sum += __shfl_xor(sum, off);
  const float inv = 1.0f / sum;
  bf16x8 o;
#pragma unroll
  for (int i = 0; i < 8; ++i) o[i] = (__bf16)(e[i] * inv);
  ((bf16x8*)(P + (long)row * DIMC))[lane] = o;
}

// ---------------------------------------------------------------------------
// prep: make_w (blocks 0..1023) + streaming x fp32 -> xb bf16 (blocks 1024+).
// ---------------------------------------------------------------------------
__global__ __launch_bounds__(256) void prep(
    const float* __restrict__ x, __bf16* __restrict__ xb,
    const float* __restrict__ Wq, const float* __restrict__ Wk,
    const float* __restrict__ Wv,
    __bf16* __restrict__ Wqh, __bf16* __restrict__ Wql,
    __bf16* __restrict__ Wkh, __bf16* __restrict__ Wkl,
    __bf16* __restrict__ WvT)
{
  if (blockIdx.x < 1024) {
    const int i = blockIdx.x * 256 + threadIdx.x;
    float q = Wq[i];
    __bf16 qh = (__bf16)q; Wqh[i] = qh; Wql[i] = (__bf16)(q - (float)qh);
    float k = Wk[i];
    __bf16 kh = (__bf16)k; Wkh[i] = kh; Wkl[i] = (__bf16)(k - (float)kh);
    const int e = i >> 9, c = i & 511;
    WvT[(long)c * DIMC + e] = (__bf16)Wv[i];
    return;
  }
  const long total8 = (long)BATCH * DIMC * NPT / 8;
  const long stride = (long)(gridDim.x - 1024) * 256;
  for (long i = (long)(blockIdx.x - 1024) * 256 + threadIdx.x; i < total8; i += stride) {
    const f32x4 a = ((const f32x4*)x)[2 * i];
    const f32x4 b = ((const f32x4*)x)[2 * i + 1];
    bf16x8 o;
    o[0] = (__bf16)a[0]; o[1] = (__bf16)a[1];
    o[2] = (__bf16)a[2]; o[3] = (__bf16)a[3];
    o[4] = (__bf16)b[0]; o[5] = (__bf16)b[1];
    o[6] = (__bf16)b[2]; o[7] = (__bf16)b[3];
    ((bf16x8*)xb)[i] = o;
  }
}

extern "C" void kernel_launch(void* const* d_in, const int* in_sizes, int n_in,
                              void* d_out, int out_size, void* d_ws, size_t ws_size,
                              hipStream_t stream)
{
  const float* x  = (const float*)d_in[0];
  const float* Wq = (const float*)d_in[1];
  const float* Wk = (const float*)d_in[2];
  const float* Wv = (const float*)d_in[3];
  float* out = (float*)d_out;

  char* ws = (char*)d_ws;
  size_t off = 0;
  auto alloc = [&](size_t bytes) -> void* {
    void* p = ws + off;
    off += (bytes + 255) & ~(size_t)255;
    return p;
  };
  const long s2 = (long)DIMC * DIMC;

  __bf16* xb  = (__bf16*)alloc((size_t)BATCH * DIMC * NPT * 2);
  float*  Gp  = (float*) alloc((size_t)KSPLIT * BATCH * s2 * 4);   // 128 MB
  __bf16* Gh  = (__bf16*)alloc((size_t)BATCH * s2 * 2);
  __bf16* Gl  = (__bf16*)alloc((size_t)BATCH * s2 * 2);
  __bf16* Hh  = (__bf16*)alloc((size_t)BATCH * s2 * 2);
  __bf16* Hl  = (__bf16*)alloc((size_t)BATCH * s2 * 2);
  __bf16* Wqh = (__bf16*)alloc((size_t)s2 * 2);
  __bf16* Wql = (__bf16*)alloc((size_t)s2 * 2);
  __bf16* Wkh = (__bf16*)alloc((size_t)s2 * 2);
  __bf16* Wkl = (__bf16*)alloc((size_t)s2 * 2);
  __bf16* WvT = (__bf16*)alloc((size_t)s2 * 2);
  float*  S  = (float*)Gp;    // alias: Gp dead after reduce
  __bf16* P  = Gl;            // alias: Gl dead after H-GEMM
  __bf16* Mm = Gh;            // alias: Gh dead after H-GEMM

  prep<<<3072, 256, 0, stream>>>(x, xb, Wq, Wk, Wv, Wqh, Wql, Wkh, Wkl, WvT);
  gram_split<<<1280, 256, 0, stream>>>(xb, Gp);
  gram_reduce_mirror<<<BATCH * 36, 256, 0, stream>>>(Gp, Gh, Gl);
  // H = Wq . G  (G symmetric -> NT), split output
  gemm3_nt<true><<<dim3(8, 8, BATCH), 256, 0, stream>>>(
      Wqh, Wql, Gh, Gl, (float*)nullptr, Hh, Hl, DIMC, 0L, s2, s2, 1.0f);
  // S = (1/sqrt(512)) H . Wk^T
  gemm3_nt<false><<<dim3(8, 8, BATCH), 256, 0, stream>>>(
      Hh, Hl, Wkh, Wkl, S, (__bf16*)nullptr, (__bf16*)nullptr,
      DIMC, s2, 0L, s2, 0.044194173824159216f);
  softmax_rows<<<BATCH * DIMC / 4, 256, 0, stream>>>(S, P);
  // M = P . Wv^T
  gemm_nt64x128<<<dim3(4, 8, BATCH), 256, 0, stream>>>(
      P, WvT, Mm, DIMC, s2, 0L, s2);
  // out = Mm . xb (NN, BK=64 single-buffer)
  gemm_final<<<2048, 256, 0, stream>>>(Mm, xb, out);
}

// Round 7
// 377.451 us; speedup vs baseline: 1.0771x; 1.0771x over previous
//
#include <hip/hip_runtime.h>
#include <hip/hip_bf16.h>
#include <math.h>

#define DIMC 512
#define NPT  4096
#define BATCH 16
#define KSPLIT 4

typedef __bf16 bf16x4 __attribute__((ext_vector_type(4)));
typedef __bf16 bf16x8 __attribute__((ext_vector_type(8)));
typedef float  f32x4  __attribute__((ext_vector_type(4)));

typedef const __attribute__((address_space(1))) unsigned int guint;
typedef __attribute__((address_space(3))) unsigned int luint;

__device__ inline void gl_lds16(const void* g, void* l) {
  __builtin_amdgcn_global_load_lds((guint*)g, (luint*)l, 16, 0, 0);
}

// BK=64 staging/read swizzle (rule #21: linear LDS dest for gl_lds, inverse-
// swizzled GLOBAL source, swizzled chunk index on ds_read):
//   lane l stages 16B of row (chunk*8 + l>>3), LDS slot (l&7);
//   source k-chunk = (l&7) ^ (l>>3 & 7)  -> read chunk' = c ^ (row&7).

// ---------------------------------------------------------------------------
// Gram, upper-triangle 128-tiles only, split-K x4, XCD-swizzled 1D grid.
// BK=64: 16 iters, 32 MFMA per barrier-pair.  (round-5 proven config)
// ---------------------------------------------------------------------------
__global__ __launch_bounds__(256, 3) void gram_split(
    const __bf16* __restrict__ xb, float* __restrict__ Gp)
{
  static const int TI[10] = {0,0,0,0,1,1,1,2,2,3};
  static const int TJ[10] = {0,1,2,3,1,2,3,2,3,3};
  const int id = blockIdx.x;              // 640 = 8 XCD * 8 pair-groups * 10 tiles
  const int xcd = id & 7, slot = id >> 3;
  const int g = slot / 10, t = slot % 10;
  const int pair = xcd + 8 * g;
  const int b = pair >> 2, s = pair & 3;
  const int m0 = TI[t] * 128, n0 = TJ[t] * 128;

  const __bf16* A = xb + (long)b * DIMC * NPT;
  float* C = Gp + (long)pair * DIMC * DIMC;

  __shared__ alignas(16) __bf16 As[128 * 64];
  __shared__ alignas(16) __bf16 Bs[128 * 64];

  const int tid  = threadIdx.x;
  const int wave = tid >> 6, lane = tid & 63;
  const int wr = wave >> 1, wc = wave & 1;
  const int q = lane >> 4, p = lane & 15;
  const int r8 = lane >> 3;
  const int sk8 = (((lane & 7) ^ (r8 & 7)) * 8);   // swizzled source k-offset
  const int px = p & 7;

  f32x4 acc[4][4];
#pragma unroll
  for (int i = 0; i < 4; ++i)
#pragma unroll
    for (int j = 0; j < 4; ++j) acc[i][j] = (f32x4){0.f, 0.f, 0.f, 0.f};

  const __bf16* gA = A + (long)m0 * NPT;
  const __bf16* gB = A + (long)n0 * NPT;
  const int kbeg = s * (NPT / KSPLIT), kend = kbeg + NPT / KSPLIT;

  for (int k0 = kbeg; k0 < kend; k0 += 64) {
    __syncthreads();
#pragma unroll
    for (int h = 0; h < 4; ++h) {
      const int chunk = wave + h * 4;                 // 0..15, rows chunk*8..+8
      gl_lds16(gA + (long)(chunk * 8 + r8) * NPT + k0 + sk8, &As[chunk * 512]);
      gl_lds16(gB + (long)(chunk * 8 + r8) * NPT + k0 + sk8, &Bs[chunk * 512]);
    }
    __syncthreads();

#pragma unroll
    for (int kk = 0; kk < 2; ++kk) {
      bf16x8 af[4], bfv[4];
#pragma unroll
      for (int i = 0; i < 4; ++i)
        af[i] = ((const bf16x8*)As)[(wr * 64 + i * 16 + p) * 8 + ((kk * 4 + q) ^ px)];
#pragma unroll
      for (int j = 0; j < 4; ++j)
        bfv[j] = ((const bf16x8*)Bs)[(wc * 64 + j * 16 + p) * 8 + ((kk * 4 + q) ^ px)];
#pragma unroll
      for (int i = 0; i < 4; ++i)
#pragma unroll
        for (int j = 0; j < 4; ++j)
          acc[i][j] = __builtin_amdgcn_mfma_f32_16x16x32_bf16(af[i], bfv[j], acc[i][j], 0, 0, 0);
    }
  }

#pragma unroll
  for (int i = 0; i < 4; ++i) {
    const int row = m0 + wr * 64 + i * 16 + q * 4;
#pragma unroll
    for (int j = 0; j < 4; ++j) {
      const int col = n0 + wc * 64 + j * 16 + p;
#pragma unroll
      for (int r = 0; r < 4; ++r)
        C[(long)(row + r) * DIMC + col] = acc[i][j][r];
    }
  }
}

// ---------------------------------------------------------------------------
// Reduce split-K partials of upper 64-tiles, emit Gh/Gl hi/lo, mirror lower.
// ---------------------------------------------------------------------------
__global__ __launch_bounds__(256) void gram_reduce_mirror(
    const float* __restrict__ Gp, __bf16* __restrict__ Gh, __bf16* __restrict__ Gl)
{
  const int bid = blockIdx.x;
  const int b = bid / 36;
  int rem = bid % 36, I = 0;
  while (rem >= 8 - I) { rem -= 8 - I; ++I; }
  const int J = I + rem;

  __shared__ float T[64][65];
  const int tid = threadIdx.x;
  const int r = tid >> 2, c0 = (tid & 3) * 16;

  float v[16];
#pragma unroll
  for (int e = 0; e < 16; ++e) v[e] = 0.f;
#pragma unroll
  for (int s = 0; s < KSPLIT; ++s) {
    const float* src = Gp + (long)(b * KSPLIT + s) * DIMC * DIMC
                          + (long)(I * 64 + r) * DIMC + J * 64 + c0;
#pragma unroll
    for (int q = 0; q < 4; ++q) {
      float4 t4 = ((const float4*)src)[q];
      v[q * 4 + 0] += t4.x; v[q * 4 + 1] += t4.y;
      v[q * 4 + 2] += t4.z; v[q * 4 + 3] += t4.w;
    }
  }

  const long gbase = (long)b * DIMC * DIMC;
#pragma unroll
  for (int q = 0; q < 4; ++q) {
    bf16x4 h, l;
#pragma unroll
    for (int e = 0; e < 4; ++e) {
      float f = v[q * 4 + e];
      __bf16 hh = (__bf16)f;
      h[e] = hh; l[e] = (__bf16)(f - (float)hh);
    }
    const long o = gbase + (long)(I * 64 + r) * DIMC + J * 64 + c0 + q * 4;
    *(bf16x4*)(Gh + o) = h;
    *(bf16x4*)(Gl + o) = l;
  }
#pragma unroll
  for (int e = 0; e < 16; ++e) T[r][c0 + e] = v[e];
  __syncthreads();
  if (I != J) {
#pragma unroll
    for (int q = 0; q < 4; ++q) {
      bf16x4 h, l;
#pragma unroll
      for (int e = 0; e < 4; ++e) {
        float f = T[c0 + q * 4 + e][r];
        __bf16 hh = (__bf16)f;
        h[e] = hh; l[e] = (__bf16)(f - (float)hh);
      }
      const long o = gbase + (long)(J * 64 + r) * DIMC + I * 64 + c0 + q * 4;
      *(bf16x4*)(Gh + o) = h;
      *(bf16x4*)(Gl + o) = l;
    }
  }
}

// ---------------------------------------------------------------------------
// 3-term hi/lo NT GEMM, 64M x 128N tile, BK=64: 8 iters, 48 MFMA/barrier-pair.
// (round-5 proven config)
// ---------------------------------------------------------------------------
template <bool SPLIT_OUT>
__global__ __launch_bounds__(256, 2) void gemm3_nt(
    const __bf16* __restrict__ Ah, const __bf16* __restrict__ Al,
    const __bf16* __restrict__ Bh, const __bf16* __restrict__ Bl,
    float* __restrict__ Cf, __bf16* __restrict__ Ch, __bf16* __restrict__ Cl,
    int K, long sA, long sB, long sC, float alpha)
{
  const int b = blockIdx.z;
  Ah += (long)b * sA;  Al += (long)b * sA;
  Bh += (long)b * sB;  Bl += (long)b * sB;
  const int m0 = blockIdx.y * 64, n0 = blockIdx.x * 128;

  __shared__ alignas(16) __bf16 sAh[64 * 64],  sAl[64 * 64];
  __shared__ alignas(16) __bf16 sBh[128 * 64], sBl[128 * 64];

  const int tid  = threadIdx.x;
  const int wave = tid >> 6, lane = tid & 63;
  const int wr = wave >> 1, wc = wave & 1;
  const int q = lane >> 4, p = lane & 15;
  const int r8 = lane >> 3;
  const int sk8 = (((lane & 7) ^ (r8 & 7)) * 8);
  const int px = p & 7;

  f32x4 acc[2][4];
#pragma unroll
  for (int i = 0; i < 2; ++i)
#pragma unroll
    for (int j = 0; j < 4; ++j) acc[i][j] = (f32x4){0.f, 0.f, 0.f, 0.f};

  for (int k0 = 0; k0 < K; k0 += 64) {
    __syncthreads();
#pragma unroll
    for (int h = 0; h < 2; ++h) {
      const int chunk = wave + h * 4;                 // 0..7, rows chunk*8..+8
      const long arow = (long)(m0 + chunk * 8 + r8) * K + k0 + sk8;
      gl_lds16(Ah + arow, &sAh[chunk * 512]);
      gl_lds16(Al + arow, &sAl[chunk * 512]);
    }
#pragma unroll
    for (int h = 0; h < 4; ++h) {
      const int chunk = wave + h * 4;                 // 0..15
      const long brow = (long)(n0 + chunk * 8 + r8) * K + k0 + sk8;
      gl_lds16(Bh + brow, &sBh[chunk * 512]);
      gl_lds16(Bl + brow, &sBl[chunk * 512]);
    }
    __syncthreads();

#pragma unroll
    for (int kk = 0; kk < 2; ++kk) {
      bf16x8 fah[2], fal[2], fbh[4], fbl[4];
#pragma unroll
      for (int i = 0; i < 2; ++i) {
        const int idx = (wr * 32 + i * 16 + p) * 8 + ((kk * 4 + q) ^ px);
        fah[i] = ((const bf16x8*)sAh)[idx];
        fal[i] = ((const bf16x8*)sAl)[idx];
      }
#pragma unroll
      for (int j = 0; j < 4; ++j) {
        const int idx = (wc * 64 + j * 16 + p) * 8 + ((kk * 4 + q) ^ px);
        fbh[j] = ((const bf16x8*)sBh)[idx];
        fbl[j] = ((const bf16x8*)sBl)[idx];
      }
#pragma unroll
      for (int i = 0; i < 2; ++i)
#pragma unroll
        for (int j = 0; j < 4; ++j) {
          acc[i][j] = __builtin_amdgcn_mfma_f32_16x16x32_bf16(fah[i], fbh[j], acc[i][j], 0, 0, 0);
          acc[i][j] = __builtin_amdgcn_mfma_f32_16x16x32_bf16(fah[i], fbl[j], acc[i][j], 0, 0, 0);
          acc[i][j] = __builtin_amdgcn_mfma_f32_16x16x32_bf16(fal[i], fbh[j], acc[i][j], 0, 0, 0);
        }
    }
  }

#pragma unroll
  for (int i = 0; i < 2; ++i) {
    const int row = m0 + wr * 32 + i * 16 + q * 4;
#pragma unroll
    for (int j = 0; j < 4; ++j) {
      const int col = n0 + wc * 64 + j * 16 + p;
#pragma unroll
      for (int r = 0; r < 4; ++r) {
        const float f = acc[i][j][r] * alpha;
        const long o = (long)b * sC + (long)(row + r) * DIMC + col;
        if (SPLIT_OUT) {
          __bf16 hh = (__bf16)f;
          Ch[o] = hh;
          Cl[o] = (__bf16)(f - (float)hh);
        } else {
          Cf[o] = f;
        }
      }
    }
  }
}

// ---------------------------------------------------------------------------
// Single-term NT GEMM bf16, 64M x 128N tile (M = P . Wv^T). BK=64: 8 iters.
// (round-5 proven config)
// ---------------------------------------------------------------------------
__global__ __launch_bounds__(256, 2) void gemm_nt64x128(
    const __bf16* __restrict__ A, const __bf16* __restrict__ B,
    __bf16* __restrict__ C, int K, long sA, long sB, long sC)
{
  const int b = blockIdx.z;
  A += (long)b * sA;  B += (long)b * sB;  C += (long)b * sC;
  const int m0 = blockIdx.y * 64, n0 = blockIdx.x * 128;

  __shared__ alignas(16) __bf16 As[64 * 64];
  __shared__ alignas(16) __bf16 Bs[128 * 64];

  const int tid  = threadIdx.x;
  const int wave = tid >> 6, lane = tid & 63;
  const int wr = wave >> 1, wc = wave & 1;
  const int q = lane >> 4, p = lane & 15;
  const int r8 = lane >> 3;
  const int sk8 = (((lane & 7) ^ (r8 & 7)) * 8);
  const int px = p & 7;

  f32x4 acc[2][4];
#pragma unroll
  for (int i = 0; i < 2; ++i)
#pragma unroll
    for (int j = 0; j < 4; ++j) acc[i][j] = (f32x4){0.f, 0.f, 0.f, 0.f};

  for (int k0 = 0; k0 < K; k0 += 64) {
    __syncthreads();
#pragma unroll
    for (int h = 0; h < 2; ++h) {
      const int chunk = wave + h * 4;
      gl_lds16(A + (long)(m0 + chunk * 8 + r8) * K + k0 + sk8, &As[chunk * 512]);
    }
#pragma unroll
    for (int h = 0; h < 4; ++h) {
      const int chunk = wave + h * 4;
      gl_lds16(B + (long)(n0 + chunk * 8 + r8) * K + k0 + sk8, &Bs[chunk * 512]);
    }
    __syncthreads();

#pragma unroll
    for (int kk = 0; kk < 2; ++kk) {
      bf16x8 af[2], bfv[4];
#pragma unroll
      for (int i = 0; i < 2; ++i)
        af[i] = ((const bf16x8*)As)[(wr * 32 + i * 16 + p) * 8 + ((kk * 4 + q) ^ px)];
#pragma unroll
      for (int j = 0; j < 4; ++j)
        bfv[j] = ((const bf16x8*)Bs)[(wc * 64 + j * 16 + p) * 8 + ((kk * 4 + q) ^ px)];
#pragma unroll
      for (int i = 0; i < 2; ++i)
#pragma unroll
        for (int j = 0; j < 4; ++j)
          acc[i][j] = __builtin_amdgcn_mfma_f32_16x16x32_bf16(af[i], bfv[j], acc[i][j], 0, 0, 0);
    }
  }

#pragma unroll
  for (int i = 0; i < 2; ++i) {
    const int row = m0 + wr * 32 + i * 16 + q * 4;
#pragma unroll
    for (int j = 0; j < 4; ++j) {
      const int col = n0 + wc * 64 + j * 16 + p;
#pragma unroll
      for (int r = 0; r < 4; ++r)
        C[(long)(row + r) * DIMC + col] = (__bf16)acc[i][j][r];
    }
  }
}

// ---------------------------------------------------------------------------
// Final GEMM (NN, direct from xb): out_b[d,n] = sum_c Mm_b[d,c] xb_b[c,n].
// BK=64 single-buffer, reg-packed transposed B (stride-34 dword rows).
// Round-7 change: B load/pack split into two 4-row groups (live rd 16->8
// VGPR) to fit the 128-VGPR cap, enabling 4 blocks/CU (LDS 33.4KB x4 fits).
// ---------------------------------------------------------------------------
__global__ __launch_bounds__(256, 4) void gemm_final(
    const __bf16* __restrict__ Mm, const __bf16* __restrict__ xb,
    float* __restrict__ out)
{
  const int id = blockIdx.x;
  const int xcd = id & 7, slot = id >> 3;
  const int g = slot >> 7, tile = slot & 127;
  const int b = xcd + 8 * g;
  const int m0 = (tile >> 5) * 128, n0 = (tile & 31) * 128;

  const __bf16* A = Mm + (long)b * DIMC * DIMC;
  const __bf16* B = xb + (long)b * DIMC * NPT;
  float* C = out + (long)b * DIMC * NPT;
  const int K = DIMC;

  __shared__ alignas(16) __bf16 As[128 * 64];
  __shared__ alignas(16) unsigned int Bs[128 * 34];   // [n][c-dword], stride 34

  const int tid  = threadIdx.x;
  const int wave = tid >> 6, lane = tid & 63;
  const int wr = wave >> 1, wc = wave & 1;
  const int q = lane >> 4, p = lane & 15;
  const int r8 = lane >> 3;
  const int sk8 = (((lane & 7) ^ (r8 & 7)) * 8);
  const int px = p & 7;

  const int ng = tid & 31;    // n quad: n_local = ng*4 .. +3
  const int cg = tid >> 5;    // c octet: c_local = cg*8 .. +7

  f32x4 acc[4][4];
#pragma unroll
  for (int i = 0; i < 4; ++i)
#pragma unroll
    for (int j = 0; j < 4; ++j) acc[i][j] = (f32x4){0.f, 0.f, 0.f, 0.f};

  const __bf16* gA = A + (long)m0 * K;
  const __bf16* gBrow = B + n0 + ng * 4;

  for (int k0 = 0; k0 < K; k0 += 64) {
    __syncthreads();
#pragma unroll
    for (int h = 0; h < 4; ++h) {
      const int chunk = wave + h * 4;                 // 0..15
      gl_lds16(gA + (long)(chunk * 8 + r8) * K + k0 + sk8, &As[chunk * 512]);
    }
    // B tile: 64 c-rows x 128 n. 8 c-rows x 4 n per thread, in TWO groups of
    // 4 rows to keep live registers low (4 blocks/CU).
#pragma unroll
    for (int grp = 0; grp < 2; ++grp) {
      uint2 rd[4];
#pragma unroll
      for (int r = 0; r < 4; ++r)
        rd[r] = *(const uint2*)(gBrow + (long)(k0 + cg * 8 + grp * 4 + r) * NPT);
#pragma unroll
      for (int nn = 0; nn < 4; ++nn) {
        const unsigned int s0 = (nn < 2) ? rd[0].x : rd[0].y;
        const unsigned int s1 = (nn < 2) ? rd[1].x : rd[1].y;
        const unsigned int s2 = (nn < 2) ? rd[2].x : rd[2].y;
        const unsigned int s3 = (nn < 2) ? rd[3].x : rd[3].y;
        unsigned int o01, o23;
        if (nn & 1) {
          o01 = (s0 >> 16) | (s1 & 0xffff0000u);
          o23 = (s2 >> 16) | (s3 & 0xffff0000u);
        } else {
          o01 = (s0 & 0xffffu) | (s1 << 16);
          o23 = (s2 & 0xffffu) | (s3 << 16);
        }
        uint2 o; o.x = o01; o.y = o23;
        *(uint2*)&Bs[(ng * 4 + nn) * 34 + cg * 4 + grp * 2] = o;  // ds_write_b64
      }
    }
    __syncthreads();

#pragma unroll
    for (int kk = 0; kk < 2; ++kk) {
      bf16x8 af[4], bfv[4];
#pragma unroll
      for (int i = 0; i < 4; ++i)
        af[i] = ((const bf16x8*)As)[(wr * 64 + i * 16 + p) * 8 + ((kk * 4 + q) ^ px)];
#pragma unroll
      for (int j = 0; j < 4; ++j) {
        const unsigned int* bp = &Bs[(wc * 64 + j * 16 + p) * 34 + kk * 16 + q * 4];
        const uint2 lo = *(const uint2*)bp;
        const uint2 hi = *(const uint2*)(bp + 2);
        union { uint4 u; bf16x8 v; } cvt;
        cvt.u.x = lo.x; cvt.u.y = lo.y; cvt.u.z = hi.x; cvt.u.w = hi.y;
        bfv[j] = cvt.v;
      }
#pragma unroll
      for (int i = 0; i < 4; ++i)
#pragma unroll
        for (int j = 0; j < 4; ++j)
          acc[i][j] = __builtin_amdgcn_mfma_f32_16x16x32_bf16(af[i], bfv[j], acc[i][j], 0, 0, 0);
    }
  }

#pragma unroll
  for (int i = 0; i < 4; ++i) {
    const int row = m0 + wr * 64 + i * 16 + q * 4;
#pragma unroll
    for (int j = 0; j < 4; ++j) {
      const int col = n0 + wc * 64 + j * 16 + p;
#pragma unroll
      for (int r = 0; r < 4; ++r)
        C[(long)(row + r) * NPT + col] = acc[i][j][r];
    }
  }
}

// ---------------------------------------------------------------------------
// Row softmax over 512 cols, fp32 in -> bf16 out. One wave per row.
// ---------------------------------------------------------------------------
__global__ __launch_bounds__(256) void softmax_rows(
    const float* __restrict__ S, __bf16* __restrict__ P)
{
  const int row = blockIdx.x * 4 + (threadIdx.x >> 6);
  const int lane = threadIdx.x & 63;
  const float4* s4 = (const float4*)(S + (long)row * DIMC);
  float4 a = s4[lane * 2], b = s4[lane * 2 + 1];
  float v[8] = {a.x, a.y, a.z, a.w, b.x, b.y, b.z, b.w};
  float m = v[0];
#pragma unroll
  for (int i = 1; i < 8; ++i) m = fmaxf(m, v[i]);
#pragma unroll
  for (int off = 32; off > 0; off >>= 1) m = fmaxf(m, __shfl_xor(m, off));
  float e[8], sum = 0.f;
#pragma unroll
  for (int i = 0; i < 8; ++i) { e[i] = expf(v[i] - m); sum += e[i]; }
#pragma unroll
  for (int off = 32; off > 0; off >>= 1) sum += __shfl_xor(sum, off);
  const float inv = 1.0f / sum;
  bf16x8 o;
#pragma unroll
  for (int i = 0; i < 8; ++i) o[i] = (__bf16)(e[i] * inv);
  ((bf16x8*)(P + (long)row * DIMC))[lane] = o;
}

// ---------------------------------------------------------------------------
// prep: make_w (blocks 0..1023) + streaming x fp32 -> xb bf16 (blocks 1024+).
// ---------------------------------------------------------------------------
__global__ __launch_bounds__(256) void prep(
    const float* __restrict__ x, __bf16* __restrict__ xb,
    const float* __restrict__ Wq, const float* __restrict__ Wk,
    const float* __restrict__ Wv,
    __bf16* __restrict__ Wqh, __bf16* __restrict__ Wql,
    __bf16* __restrict__ Wkh, __bf16* __restrict__ Wkl,
    __bf16* __restrict__ WvT)
{
  if (blockIdx.x < 1024) {
    const int i = blockIdx.x * 256 + threadIdx.x;
    float q = Wq[i];
    __bf16 qh = (__bf16)q; Wqh[i] = qh; Wql[i] = (__bf16)(q - (float)qh);
    float k = Wk[i];
    __bf16 kh = (__bf16)k; Wkh[i] = kh; Wkl[i] = (__bf16)(k - (float)kh);
    const int e = i >> 9, c = i & 511;
    WvT[(long)c * DIMC + e] = (__bf16)Wv[i];
    return;
  }
  const long total8 = (long)BATCH * DIMC * NPT / 8;
  const long stride = (long)(gridDim.x - 1024) * 256;
  for (long i = (long)(blockIdx.x - 1024) * 256 + threadIdx.x; i < total8; i += stride) {
    const f32x4 a = ((const f32x4*)x)[2 * i];
    const f32x4 b = ((const f32x4*)x)[2 * i + 1];
    bf16x8 o;
    o[0] = (__bf16)a[0]; o[1] = (__bf16)a[1];
    o[2] = (__bf16)a[2]; o[3] = (__bf16)a[3];
    o[4] = (__bf16)b[0]; o[5] = (__bf16)b[1];
    o[6] = (__bf16)b[2]; o[7] = (__bf16)b[3];
    ((bf16x8*)xb)[i] = o;
  }
}

extern "C" void kernel_launch(void* const* d_in, const int* in_sizes, int n_in,
                              void* d_out, int out_size, void* d_ws, size_t ws_size,
                              hipStream_t stream)
{
  const float* x  = (const float*)d_in[0];
  const float* Wq = (const float*)d_in[1];
  const float* Wk = (const float*)d_in[2];
  const float* Wv = (const float*)d_in[3];
  float* out = (float*)d_out;

  char* ws = (char*)d_ws;
  size_t off = 0;
  auto alloc = [&](size_t bytes) -> void* {
    void* p = ws + off;
    off += (bytes + 255) & ~(size_t)255;
    return p;
  };
  const long s2 = (long)DIMC * DIMC;

  __bf16* xb  = (__bf16*)alloc((size_t)BATCH * DIMC * NPT * 2);
  float*  Gp  = (float*) alloc((size_t)KSPLIT * BATCH * s2 * 4);
  __bf16* Gh  = (__bf16*)alloc((size_t)BATCH * s2 * 2);
  __bf16* Gl  = (__bf16*)alloc((size_t)BATCH * s2 * 2);
  __bf16* Hh  = (__bf16*)alloc((size_t)BATCH * s2 * 2);
  __bf16* Hl  = (__bf16*)alloc((size_t)BATCH * s2 * 2);
  __bf16* Wqh = (__bf16*)alloc((size_t)s2 * 2);
  __bf16* Wql = (__bf16*)alloc((size_t)s2 * 2);
  __bf16* Wkh = (__bf16*)alloc((size_t)s2 * 2);
  __bf16* Wkl = (__bf16*)alloc((size_t)s2 * 2);
  __bf16* WvT = (__bf16*)alloc((size_t)s2 * 2);
  float*  S  = (float*)Gp;    // alias: Gp dead after reduce
  __bf16* P  = Gl;            // alias: Gl dead after H-GEMM
  __bf16* Mm = Gh;            // alias: Gh dead after H-GEMM

  prep<<<3072, 256, 0, stream>>>(x, xb, Wq, Wk, Wv, Wqh, Wql, Wkh, Wkl, WvT);
  gram_split<<<640, 256, 0, stream>>>(xb, Gp);
  gram_reduce_mirror<<<BATCH * 36, 256, 0, stream>>>(Gp, Gh, Gl);
  // H = Wq . G  (G symmetric -> NT), split output
  gemm3_nt<true><<<dim3(4, 8, BATCH), 256, 0, stream>>>(
      Wqh, Wql, Gh, Gl, (float*)nullptr, Hh, Hl, DIMC, 0L, s2, s2, 1.0f);
  // S = (1/sqrt(512)) H . Wk^T
  gemm3_nt<false><<<dim3(4, 8, BATCH), 256, 0, stream>>>(
      Hh, Hl, Wkh, Wkl, S, (__bf16*)nullptr, (__bf16*)nullptr,
      DIMC, s2, 0L, s2, 0.044194173824159216f);
  softmax_rows<<<BATCH * DIMC / 4, 256, 0, stream>>>(S, P);
  // M = P . Wv^T
  gemm_nt64x128<<<dim3(4, 8, BATCH), 256, 0, stream>>>(
      P, WvT, Mm, DIMC, s2, 0L, s2);
  // out = Mm . xb (NN, BK=64 single-buffer, 4 blocks/CU)
  gemm_final<<<2048, 256, 0, stream>>>(Mm, xb, out);
}